// Round 2
// baseline (366.442 us; speedup 1.0000x reference)
//
#include <hip/hip_runtime.h>
#include <hip/hip_bf16.h>
#include <stdint.h>

#define T_STEPS 64
#define B_SZ 8
#define C_DIM 64
#define V_SZ 16000
#define K_DIM 4096   // C*C
#define M_ROWS 512   // T*B
#define BN 64
#define BK 32
#define NITER (K_DIM / BK)          // 128
#define ABYTES (M_ROWS * BK * 2)    // 32768 (A tile bf16, layout [g][row][16B])
#define WBYTES (BN * BK * 4)        // 8192  (W tile f32, layout [g][col][32B], XOR-swizzled)
#define BUFBYTES (ABYTES + WBYTES)  // 40960

typedef __bf16 bf16x8 __attribute__((ext_vector_type(8)));
typedef float f32x4 __attribute__((ext_vector_type(4)));

__device__ __forceinline__ void gll16(const void* g, void* l) {
  __builtin_amdgcn_global_load_lds(
      (const __attribute__((address_space(1))) void*)g,
      (__attribute__((address_space(3))) void*)l, 16, 0, 0);
}

// ---------------- Kernel 1: sequential ctx recurrence ----------------
__global__ void ctx_kernel(const int* __restrict__ tokens,
                           const float* __restrict__ emb_ctx,
                           const float* __restrict__ beta_mult,
                           const float* __restrict__ beta_power,
                           float* __restrict__ ctx_hist) {
  const int b = blockIdx.x;
  const int d = threadIdx.x;
  const float bm = beta_mult[0];
  const float bp = beta_power[0];
  float ctx = 0.0f;
  for (int t = 0; t < T_STEPS; ++t) {
    const int tok = tokens[t * B_SZ + b];
    const float ce = emb_ctx[tok * C_DIM + d];
    float ne2 = ce * ce;
    float c2 = ctx * ctx;
#pragma unroll
    for (int s = 32; s > 0; s >>= 1) {
      ne2 += __shfl_xor(ne2, s, 64);
      c2 += __shfl_xor(c2, s, 64);
    }
    const float ne = sqrtf(ne2);
    const float nc = sqrtf(c2);
    float beta = powf(bm * (ne / (ne + nc)), bp);  // ALPHA == 1
    beta = fminf(fmaxf(beta, 0.0f), 1.0f);
    ctx = (1.0f - beta) * ctx + beta * ce;
    ctx_hist[(t * B_SZ + b) * C_DIM + d] = ctx;
  }
}

// ---------------- Kernel 2: build M[m, c*64+d] = ae[m][c] * ctx[m][d] (bf16) ----
__global__ void build_m(const int* __restrict__ tokens,
                        const float* __restrict__ emb_act,
                        const float* __restrict__ ctx_hist,
                        short* __restrict__ Mout) {
  const int m = blockIdx.x;
  const int tid = threadIdx.x;
  __shared__ float ctxs[C_DIM];
  __shared__ float aes[C_DIM];
  const int t = m >> 3, b = m & 7;
  const int tok = tokens[t * B_SZ + b];
  if (tid < C_DIM) {
    ctxs[tid] = ctx_hist[m * C_DIM + tid];
    aes[tid] = emb_act[tok * C_DIM + tid];
  }
  __syncthreads();
  const int c = tid >> 1;
  const int dh = (tid & 1) * 32;
  const float ae = aes[c];
  short* dst = Mout + (size_t)m * K_DIM + c * C_DIM + dh;
#pragma unroll
  for (int q = 0; q < 4; ++q) {
    bf16x8 v;
#pragma unroll
    for (int jj = 0; jj < 8; ++jj) v[jj] = (__bf16)(ae * ctxs[dh + q * 8 + jj]);
    *(bf16x8*)(void*)(dst + q * 8) = v;
  }
}

// ---------------- Kernel 3: GEMM out[512,16000] = M[512,4096] * W^T ------------
// BM=512 (all of M, so each W panel is read exactly once), BN=64, BK=32.
// 4 waves, each owns 128 M-rows x 64 N-cols (acc = 8x4 f32x4 = 128 VGPR).
// 3-buffer LDS pipeline, prefetch depth 2, counted vmcnt(20) (T3+T4).
// A LDS layout [g][row][16B]: conflict-free for both gll16 dest and frag read.
// W LDS layout [g][col][32B] ^ ((col&4)<<2): conflict-free frag reads;
// inverse-swizzle applied to the global source (rule #21).
__device__ __forceinline__ void compute_tile(const char* Abuf, const char* Bbuf,
                                             f32x4 (&acc)[8][4], int lane, int w) {
  const int lrow = lane & 15;
  const int g = lane >> 4;
  bf16x8 a[8];
#pragma unroll
  for (int fm = 0; fm < 8; ++fm) {
    const int row = w * 128 + fm * 16 + lrow;
    a[fm] = *(const bf16x8*)(Abuf + g * 8192 + row * 16);
  }
#pragma unroll
  for (int fn = 0; fn < 4; ++fn) {
    const int col = fn * 16 + lrow;
    const int x = (col & 4) << 2;
    const f32x4 b0 = *(const f32x4*)(Bbuf + g * 2048 + ((col * 32) ^ x));
    const f32x4 b1 = *(const f32x4*)(Bbuf + g * 2048 + ((col * 32 + 16) ^ x));
    bf16x8 bv;
    bv[0] = (__bf16)b0[0]; bv[1] = (__bf16)b0[1];
    bv[2] = (__bf16)b0[2]; bv[3] = (__bf16)b0[3];
    bv[4] = (__bf16)b1[0]; bv[5] = (__bf16)b1[1];
    bv[6] = (__bf16)b1[2]; bv[7] = (__bf16)b1[3];
#pragma unroll
    for (int fm = 0; fm < 8; ++fm)
      acc[fm][fn] =
          __builtin_amdgcn_mfma_f32_16x16x32_bf16(a[fm], bv, acc[fm][fn], 0, 0, 0);
  }
}

__global__ __launch_bounds__(256, 1)
void gemm_kernel(const short* __restrict__ A, const float* __restrict__ W,
                 float* __restrict__ out) {
  __shared__ __align__(1024) char smem[3 * BUFBYTES];  // 120 KB
  const int tid = threadIdx.x;
  const int lane = tid & 63;
  const int w = tid >> 6;
  const int n0 = blockIdx.x * BN;

  // Per-thread global source pointers for staging (advance each K-iter).
  const char* const Ac = (const char*)A;
  const char* const Wc = (const char*)W;
  const char* asrc[8];
#pragma unroll
  for (int s = 0; s < 8; ++s) {
    const int row = ((s & 1) << 8) + tid;     // dest L = s*4096 + tid*16
    asrc[s] = Ac + (size_t)row * (K_DIM * 2) + (s >> 1) * 16;
  }
  const char* wsrc[2];
#pragma unroll
  for (int s = 0; s < 2; ++s) {
    const int L = s * 4096 + tid * 16;        // linear dest within W region
    const int g = L >> 11;
    const int r = L & 2047;
    const int xr = r ^ ((r >> 3) & 16);       // inverse of read-side XOR
    const int col = xr >> 5;
    const int half = (xr >> 4) & 1;
    wsrc[s] = Wc + (size_t)(n0 + col) * (K_DIM * 4) + g * 32 + half * 16;
  }

  f32x4 acc[8][4];
#pragma unroll
  for (int fm = 0; fm < 8; ++fm)
#pragma unroll
    for (int fn = 0; fn < 4; ++fn) acc[fm][fn] = (f32x4){0.f, 0.f, 0.f, 0.f};

  // STAGE: 8 A-issues + 2 W-issues (10 x 16B/thread), then advance sources.
  auto STAGE = [&](int b) {
    char* dst = smem + b * BUFBYTES;
#pragma unroll
    for (int s = 0; s < 8; ++s) {
      gll16(asrc[s], dst + s * 4096 + tid * 16);
      asrc[s] += BK * 2;
    }
#pragma unroll
    for (int s = 0; s < 2; ++s) {
      gll16(wsrc[s], dst + ABYTES + s * 4096 + tid * 16);
      wsrc[s] += BK * 4;
    }
  };

  STAGE(0);
  STAGE(1);

  int cur = 0;
#pragma unroll 1
  for (int kt = 0; kt < NITER - 2; ++kt) {
    const int stg = (cur >= 1) ? cur - 1 : 2;  // (cur+2)%3 — buffer freed last iter
    STAGE(stg);
    asm volatile("s_waitcnt vmcnt(20)" ::: "memory");  // tile `cur` landed
    __builtin_amdgcn_s_barrier();
    __builtin_amdgcn_sched_barrier(0);
    compute_tile(smem + cur * BUFBYTES, smem + cur * BUFBYTES + ABYTES, acc, lane, w);
    asm volatile("s_waitcnt lgkmcnt(0)" ::: "memory");  // reads done before overwrite
    __builtin_amdgcn_sched_barrier(0);
    __builtin_amdgcn_s_barrier();
    cur = (cur < 2) ? cur + 1 : 0;
  }
  // kt = NITER-2: 20 outstanding, wait for the older 10
  asm volatile("s_waitcnt vmcnt(10)" ::: "memory");
  __builtin_amdgcn_s_barrier();
  __builtin_amdgcn_sched_barrier(0);
  compute_tile(smem + cur * BUFBYTES, smem + cur * BUFBYTES + ABYTES, acc, lane, w);
  cur = (cur < 2) ? cur + 1 : 0;
  // kt = NITER-1
  asm volatile("s_waitcnt vmcnt(0)" ::: "memory");
  __builtin_amdgcn_s_barrier();
  __builtin_amdgcn_sched_barrier(0);
  compute_tile(smem + cur * BUFBYTES, smem + cur * BUFBYTES + ABYTES, acc, lane, w);

  // Epilogue: C/D layout col = lane&15, row = (lane>>4)*4 + q.
  const int lrow = lane & 15;
  const int g = lane >> 4;
#pragma unroll
  for (int fm = 0; fm < 8; ++fm)
#pragma unroll
    for (int q = 0; q < 4; ++q) {
      const int row = w * 128 + fm * 16 + g * 4 + q;
      float* po = out + (size_t)row * V_SZ + n0 + lrow;
#pragma unroll
      for (int fn = 0; fn < 4; ++fn) po[fn * 16] = acc[fm][fn][q];
    }
}

extern "C" void kernel_launch(void* const* d_in, const int* in_sizes, int n_in,
                              void* d_out, int out_size, void* d_ws, size_t ws_size,
                              hipStream_t stream) {
  const int* tokens = (const int*)d_in[0];
  const float* emb_ctx = (const float*)d_in[1];
  const float* emb_act = (const float*)d_in[2];
  const float* W = (const float*)d_in[3];
  const float* beta_mult = (const float*)d_in[4];
  const float* beta_power = (const float*)d_in[5];
  float* out = (float*)d_out;

  short* Mbuf = (short*)d_ws;  // 512*4096*2 = 4 MB
  float* ctx_hist = (float*)((char*)d_ws + (size_t)M_ROWS * K_DIM * 2);  // 128 KB

  ctx_kernel<<<B_SZ, C_DIM, 0, stream>>>(tokens, emb_ctx, beta_mult, beta_power,
                                         ctx_hist);
  build_m<<<M_ROWS, 128, 0, stream>>>(tokens, emb_act, ctx_hist, Mbuf);
  gemm_kernel<<<V_SZ / BN, 256, 0, stream>>>(Mbuf, W, out);
}

// Round 3
// 175.002 us; speedup vs baseline: 2.0939x; 2.0939x over previous
//
#include <hip/hip_runtime.h>
#include <hip/hip_bf16.h>
#include <stdint.h>

#define T_STEPS 64
#define B_SZ 8
#define C_DIM 64
#define V_SZ 16000
#define K_DIM 4096   // C*C
#define M_ROWS 512   // T*B
#define BN 64
#define BK 32
#define NITER (K_DIM / BK)  // 128
#define ATILE_BYTES 32768   // 512 rows * 32 k * 2B, blocked [g][row][16B]

typedef __bf16 bf16x8 __attribute__((ext_vector_type(8)));
typedef __bf16 bf16x4 __attribute__((ext_vector_type(4)));
typedef float f32x4 __attribute__((ext_vector_type(4)));

// ---------------- Kernel 1: sequential ctx recurrence ----------------
__global__ void ctx_kernel(const int* __restrict__ tokens,
                           const float* __restrict__ emb_ctx,
                           const float* __restrict__ beta_mult,
                           const float* __restrict__ beta_power,
                           float* __restrict__ ctx_hist) {
  const int b = blockIdx.x;
  const int d = threadIdx.x;
  const float bm = beta_mult[0];
  const float bp = beta_power[0];
  float ctx = 0.0f;
  for (int t = 0; t < T_STEPS; ++t) {
    const int tok = tokens[t * B_SZ + b];
    const float ce = emb_ctx[tok * C_DIM + d];
    float ne2 = ce * ce;
    float c2 = ctx * ctx;
#pragma unroll
    for (int s = 32; s > 0; s >>= 1) {
      ne2 += __shfl_xor(ne2, s, 64);
      c2 += __shfl_xor(c2, s, 64);
    }
    const float ne = sqrtf(ne2);
    const float nc = sqrtf(c2);
    float beta = powf(bm * (ne / (ne + nc)), bp);  // ALPHA == 1
    beta = fminf(fmaxf(beta, 0.0f), 1.0f);
    ctx = (1.0f - beta) * ctx + beta * ce;
    ctx_hist[(t * B_SZ + b) * C_DIM + d] = ctx;
  }
}

// ---------------- Kernel 2: build M in MFMA-fragment-blocked layout ----------
// Element (row m, k) -> byte (k>>5)*32768 + ((k>>3)&3)*8192 + m*16 + (k&7)*2.
// A-tile kt is then one contiguous 32KB block, frag-ready.
__global__ void build_m(const int* __restrict__ tokens,
                        const float* __restrict__ emb_act,
                        const float* __restrict__ ctx_hist,
                        char* __restrict__ Mblk) {
  const int m = blockIdx.x;
  const int tid = threadIdx.x;
  __shared__ float ctxs[C_DIM];
  __shared__ float aes[C_DIM];
  const int t = m >> 3, b = m & 7;
  const int tok = tokens[t * B_SZ + b];
  if (tid < C_DIM) {
    ctxs[tid] = ctx_hist[m * C_DIM + tid];
    aes[tid] = emb_act[tok * C_DIM + tid];
  }
  __syncthreads();
  const int c = tid >> 1;
  const int dh = (tid & 1) * 32;
  const float ae = aes[c];
#pragma unroll
  for (int q = 0; q < 4; ++q) {
    const int k0 = c * C_DIM + dh + q * 8;
    bf16x8 v;
#pragma unroll
    for (int jj = 0; jj < 8; ++jj) v[jj] = (__bf16)(ae * ctxs[dh + q * 8 + jj]);
    *(bf16x8*)(void*)(Mblk + (size_t)(k0 >> 5) * 32768 + ((k0 >> 3) & 3) * 8192 +
                      m * 16) = v;
  }
}

// ---------------- Kernel 3: GEMM out[512,16000] = M[512,4096] * W^T ------------
// BM=512 (W read exactly once), BN=64, BK=32, 512 threads (8 waves, 64x64 each).
// A: direct global->VGPR fragments (blocked layout, L2-resident), reg dbuf.
// W: f32x4 global->reg (depth-2/3 prefetch) -> cvt bf16 -> ds_write 8B ->
//    4-slot LDS (16KB total). One lgkmcnt(0)+s_barrier per iter; no vmcnt(0).
__global__ __launch_bounds__(512, 2)
void gemm_kernel(const char* __restrict__ Ablk, const float* __restrict__ W,
                 float* __restrict__ out) {
  __shared__ char wlds[4][4096];  // [slot][g][col64][16B] bf16
  const int tid = threadIdx.x;
  const int lane = tid & 63;
  const int w = tid >> 6;
  const int lrow = lane & 15;
  const int g = lane >> 4;
  const int n0 = blockIdx.x * BN;

  // A-fragment per-lane byte offsets within a 32KB tile
  int aoff[4];
#pragma unroll
  for (int fm = 0; fm < 4; ++fm)
    aoff[fm] = g * 8192 + (w * 64 + fm * 16 + lrow) * 16;

  // W staging: thread t loads 4 consecutive f32 of row n0+(t>>3)
  const char* const Wc = (const char*)W;
  const size_t wvoff = ((size_t)(n0 + (tid >> 3)) * K_DIM + (tid & 7) * 4) * 4;
  // LDS write offset: g=(t&7)>>1, col=t>>3, half=(t&1)
  const int wldsoff = ((tid & 7) >> 1) * 1024 + (tid >> 3) * 16 + (tid & 1) * 8;

  f32x4 acc[4][4];
#pragma unroll
  for (int fm = 0; fm < 4; ++fm)
#pragma unroll
    for (int fn = 0; fn < 4; ++fn) acc[fm][fn] = (f32x4){0.f, 0.f, 0.f, 0.f};

  bf16x8 a2[2][4];
  f32x4 wr[4];

  // ---- prologue: W(0),W(1),A(0),W(2); write W-tile 0 to slot 0 ----
  wr[0] = *(const f32x4*)(Wc + wvoff);
  wr[1] = *(const f32x4*)(Wc + wvoff + 128);
#pragma unroll
  for (int fm = 0; fm < 4; ++fm) a2[0][fm] = *(const bf16x8*)(Ablk + aoff[fm]);
  wr[2] = *(const f32x4*)(Wc + wvoff + 256);
  {
    bf16x4 h;
#pragma unroll
    for (int q = 0; q < 4; ++q) h[q] = (__bf16)wr[0][q];
    *(bf16x4*)(wlds[0] + wldsoff) = h;
  }
  asm volatile("s_waitcnt lgkmcnt(0)" ::: "memory");
  __builtin_amdgcn_s_barrier();
  __builtin_amdgcn_sched_barrier(0);

#pragma unroll 1
  for (int bb = 0; bb < NITER / 4; ++bb) {
#pragma unroll
    for (int j = 0; j < 4; ++j) {
      const int kt = bb * 4 + j;
      // 1. issue A(kt+1) -> a2[(j+1)&1]   (clamped re-read on last iter)
      const int kta = (kt + 1 < NITER) ? kt + 1 : kt;
      const char* ap = Ablk + (size_t)kta * ATILE_BYTES;
#pragma unroll
      for (int fm = 0; fm < 4; ++fm)
        a2[(j + 1) & 1][fm] = *(const bf16x8*)(ap + aoff[fm]);
      // 2. issue W(kt+3) -> wr[(j+3)&3]
      const int ktw = (kt + 3 < NITER) ? kt + 3 : NITER - 1;
      wr[(j + 3) & 3] = *(const f32x4*)(Wc + wvoff + (size_t)ktw * 128);
      // 3. cvt + ds_write W(kt+1) into slot (j+1)&3
      {
        bf16x4 h;
#pragma unroll
        for (int q = 0; q < 4; ++q) h[q] = (__bf16)wr[(j + 1) & 3][q];
        *(bf16x4*)(wlds[(j + 1) & 3] + wldsoff) = h;
      }
      // 4. one barrier per iter; vmem prefetches stay in flight
      asm volatile("s_waitcnt lgkmcnt(0)" ::: "memory");
      __builtin_amdgcn_s_barrier();
      __builtin_amdgcn_sched_barrier(0);
      // 5. compute kt from wlds[j&3] + a2[j&1]
#pragma unroll
      for (int fn = 0; fn < 4; ++fn) {
        const bf16x8 bv =
            *(const bf16x8*)(wlds[j & 3] + g * 1024 + (fn * 16 + lrow) * 16);
#pragma unroll
        for (int fm = 0; fm < 4; ++fm)
          acc[fm][fn] = __builtin_amdgcn_mfma_f32_16x16x32_bf16(
              a2[j & 1][fm], bv, acc[fm][fn], 0, 0, 0);
      }
    }
  }

  // Epilogue: C/D layout col = lane&15, row = (lane>>4)*4 + q
#pragma unroll
  for (int fm = 0; fm < 4; ++fm)
#pragma unroll
    for (int q = 0; q < 4; ++q) {
      const int row = w * 64 + fm * 16 + g * 4 + q;
      float* po = out + (size_t)row * V_SZ + n0 + lrow;
#pragma unroll
      for (int fn = 0; fn < 4; ++fn) po[fn * 16] = acc[fm][fn][q];
    }
}

extern "C" void kernel_launch(void* const* d_in, const int* in_sizes, int n_in,
                              void* d_out, int out_size, void* d_ws, size_t ws_size,
                              hipStream_t stream) {
  const int* tokens = (const int*)d_in[0];
  const float* emb_ctx = (const float*)d_in[1];
  const float* emb_act = (const float*)d_in[2];
  const float* W = (const float*)d_in[3];
  const float* beta_mult = (const float*)d_in[4];
  const float* beta_power = (const float*)d_in[5];
  float* out = (float*)d_out;

  char* Mblk = (char*)d_ws;  // 4 MB, blocked layout
  float* ctx_hist = (float*)((char*)d_ws + (size_t)M_ROWS * K_DIM * 2);  // 128 KB

  ctx_kernel<<<B_SZ, C_DIM, 0, stream>>>(tokens, emb_ctx, beta_mult, beta_power,
                                         ctx_hist);
  build_m<<<M_ROWS, 128, 0, stream>>>(tokens, emb_act, ctx_hist, Mblk);
  gemm_kernel<<<V_SZ / BN, 512, 0, stream>>>(Mblk, W, out);
}